// Round 15
// baseline (145.757 us; speedup 1.0000x reference)
//
#include <hip/hip_runtime.h>
#include <hip/hip_bf16.h>
#include <cstddef>
#include <cstdint>

typedef _Float16 half_t;
typedef _Float16 half8  __attribute__((ext_vector_type(8)));
typedef _Float16 half4v __attribute__((ext_vector_type(4)));
typedef float    f32x4  __attribute__((ext_vector_type(4)));

#define SCALE 0.17677669529663687f   // 1/sqrt(32)

// workspace layout (bytes):
//   [0,        221184)   wqfrag  fragment-major qkv weights fp16 (K1 input)
//                        -- after K1, first 196608 B overwritten by mb16
//   [221184,   294912)   wofrag  fragment-major out-proj weights fp16
//   [294912,   38043648) q_raw   [wh=12288][dh=2][tm=3][lane=64][4] fp16 (q^T frags)
//   [38043648, 75792384) k_raw   same layout (k^T frags)
//   [75792384, 113541120) v_raw  same layout (V frags, tok-major rows)
//   [113541120,114327552) tinyQ  [wh][dh][16] fp16  (token-48 sliver)
//   [114327552,115113984) tinyK  [wh][dh][16] fp16
//   [115113984,115900416) tinyV  [wh][dt][16] fp16

// ---------------------------------------------------------------------------
__global__ __launch_bounds__(256) void convert_w(
    const float* __restrict__ w_qkv, const float* __restrict__ w_out,
    half_t* __restrict__ wq, half_t* __restrict__ wo)
{
    int i = blockIdx.x * 256 + threadIdx.x;
    if (i < 110592) {
        int u8 = i >> 3, e = i & 7;
        int c  = u8 & 15;
        int g  = (u8 >> 4) & 3;
        int ks = (u8 >> 6) % 6;
        int ct = u8 / 384;
        wq[i] = (half_t)w_qkv[(16 * ct + c) * 192 + ks * 32 + g * 8 + e];
    } else {
        int j = i - 110592;
        if (j < 36864) {
            int u8 = j >> 3, e = j & 7;
            int c  = u8 & 15;
            int g  = (u8 >> 4) & 3;
            int ks = (u8 >> 6) % 6;
            int q  = u8 / 384;
            wo[j] = (half_t)w_out[(16 * q + c) * 192 + ks * 32 + g * 8 + e];
        }
    }
}

// ---------------------------------------------------------------------------
// Masked relative-position bias table: mb[4][6][64][64] fp16.
// Mask class mc = 2*(nh==7) + (nw==7). Masked / padded entries = -60000.
// ---------------------------------------------------------------------------
__global__ __launch_bounds__(256) void build_bias(
    const float* __restrict__ pos_enc, half_t* __restrict__ mb)
{
    int idx = blockIdx.x * 256 + threadIdx.x;   // < 98304
    int j   = idx & 63;
    int i   = (idx >> 6) & 63;
    int hmc = idx >> 12;
    int h   = hmc % 6, mc = hmc / 6;
    float v = -60000.f;
    if (i < 49 && j < 49) {
        int yi = i / 7, xi = i - 7 * yi;
        int yj = j / 7, xj = j - 7 * yj;
        int ri = ((mc & 2) ? (yi < 4 ? 1 : 2) : 0) * 3 + ((mc & 1) ? (xi < 4 ? 1 : 2) : 0);
        int rj = ((mc & 2) ? (yj < 4 ? 1 : 2) : 0) * 3 + ((mc & 1) ? (xj < 4 ? 1 : 2) : 0);
        if (ri == rj) v = pos_enc[h * 169 + (yi - yj + 6) * 13 + (xi - xj + 6)];
    }
    mb[idx] = (half_t)v;
}

// ---------------------------------------------------------------------------
// K1: QKV projection. 2048 blocks x 256 threads = 4 waves; block = 1 window.
// Wave = (cf = wave>>1, mh = wave&1): cf=0 -> col-tiles 0..17, cf=1 -> 18..35;
// mh = token half (tokens 32mh..32mh+31). Zero LDS / zero barriers.
// 32 waves/CU (was 16) to cover L2 weight-load latency.
// q,k swapped-operand MFMA -> raw fragment layouts; coalesced half4v stores.
// ---------------------------------------------------------------------------
__global__ __launch_bounds__(256, 4) void swin_qkv(
    const float*  __restrict__ x,
    const half_t* __restrict__ wqfrag,
    const float*  __restrict__ b_qkv,
    half_t* __restrict__ qraw,
    half_t* __restrict__ kraw,
    half_t* __restrict__ vraw,
    half_t* __restrict__ tinyQ,
    half_t* __restrict__ tinyK,
    half_t* __restrict__ tinyV)
{
    const int tid  = threadIdx.x;
    const int wave = tid >> 6, lane = tid & 63;
    const int cf   = wave >> 1, mh = wave & 1;
    const int c    = lane & 15, g = lane >> 4;
    const int w    = blockIdx.x;
    const int b    = w >> 6, win = w & 63, nh = win >> 3, nw = win & 7;
    const int wh0  = w * 6;

    // ---- shifted-window gather of 32 tokens into A/B fragments -----------
    half8 xf[2][6];
    #pragma unroll
    for (int t = 0; t < 2; ++t) {
        int tok = 32 * mh + 16 * t + c;
        if (tok < 49) {
            int ty = tok / 7, tx = tok - ty * 7;
            int sy = nh * 7 + ty + 3; if (sy >= 56) sy -= 56;
            int sx = nw * 7 + tx + 3; if (sx >= 56) sx -= 56;
            const float* xr = x + ((size_t)b * 3136 + sy * 56 + sx) * 192 + g * 8;
            #pragma unroll
            for (int ks = 0; ks < 6; ++ks) {
                float4 v0 = *(const float4*)(xr + ks * 32);
                float4 v1 = *(const float4*)(xr + ks * 32 + 4);
                xf[t][ks] = (half8){(half_t)v0.x, (half_t)v0.y, (half_t)v0.z, (half_t)v0.w,
                                    (half_t)v1.x, (half_t)v1.y, (half_t)v1.z, (half_t)v1.w};
            }
        } else {
            #pragma unroll
            for (int ks = 0; ks < 6; ++ks)
                xf[t][ks] = (half8){(half_t)0.f, (half_t)0.f, (half_t)0.f, (half_t)0.f,
                                    (half_t)0.f, (half_t)0.f, (half_t)0.f, (half_t)0.f};
        }
    }

    // ---- q,k slice: swapped operands -> C = [d-rows][tok-cols] ------------
    // cf=0 handles ct 0..17 (q 0..11, k 12..17); cf=1 handles ct 18..23 (k).
    {
        const int ct0 = cf ? 18 : 0;
        const int ct1 = cf ? 24 : 18;
        #pragma unroll 6
        for (int ct = ct0; ct < ct1; ++ct) {
            const half_t* wp = wqfrag + ((size_t)ct * 384 + lane) * 8;
            half8 bfm[6];
            #pragma unroll
            for (int ks = 0; ks < 6; ++ks) bfm[ks] = *(const half8*)(wp + ks * 512);
            f32x4 a0 = (f32x4){0.f, 0.f, 0.f, 0.f};
            f32x4 a1 = (f32x4){0.f, 0.f, 0.f, 0.f};
            #pragma unroll
            for (int ks = 0; ks < 6; ++ks) {
                a0 = __builtin_amdgcn_mfma_f32_16x16x32_f16(bfm[ks], xf[0][ks], a0, 0, 0, 0);
                a1 = __builtin_amdgcn_mfma_f32_16x16x32_f16(bfm[ks], xf[1][ks], a1, 0, 0, 0);
            }
            const int kind = ct / 12, rem = ct - 12 * kind;   // 0=q, 1=k
            const int h = rem >> 1, dh = rem & 1;
            float4 bq = *(const float4*)(b_qkv + 16 * ct + 4 * g);  // bias[4g+r]
            half_t* dst = kind ? kraw : qraw;
            half_t* tny = kind ? tinyK : tinyQ;
            const size_t base = ((size_t)(wh0 + h) * 2 + dh) * 3;
            #pragma unroll
            for (int t = 0; t < 2; ++t) {
                f32x4 a = t ? a1 : a0;
                int tm = 2 * mh + t;
                half4v pv = (half4v){(half_t)(a[0] + bq.x), (half_t)(a[1] + bq.y),
                                     (half_t)(a[2] + bq.z), (half_t)(a[3] + bq.w)};
                if (tm < 3) {
                    *(half4v*)(dst + ((base + tm) * 64 + lane) * 4) = pv;
                } else if (c == 0) {
                    *(half4v*)(tny + ((wh0 + h) * 2 + dh) * 16 + 4 * g) = pv;
                }
            }
        }
    }

    // ---- v slice (cf=1 only): normal operands -> C = [tok-rows][d-cols] ---
    if (cf) {
        #pragma unroll 4
        for (int ct = 24; ct < 36; ++ct) {
            const half_t* wp = wqfrag + ((size_t)ct * 384 + lane) * 8;
            half8 bfm[6];
            #pragma unroll
            for (int ks = 0; ks < 6; ++ks) bfm[ks] = *(const half8*)(wp + ks * 512);
            f32x4 a0 = (f32x4){0.f, 0.f, 0.f, 0.f};
            f32x4 a1 = (f32x4){0.f, 0.f, 0.f, 0.f};
            #pragma unroll
            for (int ks = 0; ks < 6; ++ks) {
                a0 = __builtin_amdgcn_mfma_f32_16x16x32_f16(xf[0][ks], bfm[ks], a0, 0, 0, 0);
                a1 = __builtin_amdgcn_mfma_f32_16x16x32_f16(xf[1][ks], bfm[ks], a1, 0, 0, 0);
            }
            const int rem = ct - 24;
            const int h = rem >> 1, dh = rem & 1;
            const float bv = b_qkv[16 * ct + c];
            const size_t base = ((size_t)(wh0 + h) * 2 + dh) * 3;
            #pragma unroll
            for (int t = 0; t < 2; ++t) {
                f32x4 a = t ? a1 : a0;
                int tm = 2 * mh + t;
                if (tm < 3) {
                    half4v pv = (half4v){(half_t)(a[0] + bv), (half_t)(a[1] + bv),
                                         (half_t)(a[2] + bv), (half_t)(a[3] + bv)};
                    *(half4v*)(vraw + ((base + tm) * 64 + lane) * 4) = pv;
                } else if (g == 0) {
                    tinyV[((wh0 + h) * 2 + dh) * 16 + c] = (half_t)(a[0] + bv);
                }
            }
        }
    }
}

// ---------------------------------------------------------------------------
// K2: attention (3 heads/wave; k_raw staged in LDS; q/bias/V/tiny prefetched
// one head ahead) + out-projection (frag-major sAf) + un-shift scatter.
// grid = 2048, 512 threads = 8 waves; wave (ti, hf): heads h = 3*hf + p.
// (byte-identical to round 14)
// ---------------------------------------------------------------------------
__global__ __launch_bounds__(512, 4) void swin_attn_proj(
    const half_t* __restrict__ qraw,
    const half_t* __restrict__ kraw,
    const half_t* __restrict__ vraw,
    const half_t* __restrict__ tinyQ,
    const half_t* __restrict__ tinyK,
    const half_t* __restrict__ tinyV,
    const half_t* __restrict__ mb16,
    const half_t* __restrict__ wofrag,
    const float*  __restrict__ b_out,
    float* __restrict__ out)
{
    __shared__ __align__(16) half_t sK[1536 * 8];        // 24576 B (18432 used)
    __shared__ __align__(16) half_t sAf[6 * 4 * 64 * 8]; // 24576 B frag-major O

    const int w    = blockIdx.x;
    const int b    = w >> 6, win = w & 63, nh = win >> 3, nw = win & 7;
    const int tid  = threadIdx.x;
    const int wave = tid >> 6, lane = tid & 63;
    const int c    = lane & 15, g = lane >> 4;
    const int ti   = wave & 3, hf = wave >> 2;
    const int i_tok = 16 * ti + c;
    const int mc   = 2 * (nh == 7) + (nw == 7);

    // ---- stage this window's k_raw block (6 heads x 3072 B) into LDS -----
    {
        const half_t* src = kraw + (size_t)w * 9216;
        #pragma unroll
        for (int rnd = 0; rnd < 3; ++rnd) {
            int u = tid + rnd * 512;   // 1536 issues; tail overread benign
            __builtin_amdgcn_global_load_lds(
                (const __attribute__((address_space(1))) unsigned int*)(src + u * 8),
                (__attribute__((address_space(3))) unsigned int*)(&sK[u * 8]), 16, 0, 0);
        }
    }

    half4v qA[2], qB[2];
    half4v bA[4], bB[4];
    half4v vA[6], vB[6];
    half4v v3A[2], v3B[2];
    half4v k3A[2], k3B[2];

#define LOADH(QF, BF, VF, V3, K3, hh) do {                                        \
        const int wh_ = w * 6 + (hh);                                             \
        if (ti < 3) {                                                             \
            QF[0] = *(const half4v*)(qraw + (((size_t)wh_ * 2 + 0) * 3 + ti) * 256 + lane * 4); \
            QF[1] = *(const half4v*)(qraw + (((size_t)wh_ * 2 + 1) * 3 + ti) * 256 + lane * 4); \
        } else {                                                                  \
            QF[0] = *(const half4v*)(tinyQ + (wh_ * 2 + 0) * 16 + 4 * g);         \
            QF[1] = *(const half4v*)(tinyQ + (wh_ * 2 + 1) * 16 + 4 * g);         \
        }                                                                         \
        const half_t* mrow_ = mb16 + ((size_t)(mc * 6 + (hh)) * 64 + i_tok) * 64; \
        _Pragma("unroll")                                                         \
        for (int tj_ = 0; tj_ < 4; ++tj_)                                         \
            BF[tj_] = *(const half4v*)(mrow_ + 16 * tj_ + 4 * g);                 \
        _Pragma("unroll")                                                         \
        for (int tj_ = 0; tj_ < 3; ++tj_) {                                       \
            VF[2 * tj_]     = *(const half4v*)(vraw + (((size_t)wh_ * 2 + 0) * 3 + tj_) * 256 + lane * 4); \
            VF[2 * tj_ + 1] = *(const half4v*)(vraw + (((size_t)wh_ * 2 + 1) * 3 + tj_) * 256 + lane * 4); \
        }                                                                         \
        {                                                                         \
            half_t tv0 = tinyV[(wh_ * 2 + 0) * 16 + c];                           \
            half_t tv1 = tinyV[(wh_ * 2 + 1) * 16 + c];                           \
            V3[0] = (half4v){tv0, tv0, tv0, tv0};                                 \
            V3[1] = (half4v){tv1, tv1, tv1, tv1};                                 \
        }                                                                         \
        K3[0] = *(const half4v*)(tinyK + (wh_ * 2 + 0) * 16 + 4 * g);             \
        K3[1] = *(const half4v*)(tinyK + (wh_ * 2 + 1) * 16 + 4 * g);             \
    } while (0)

    // prefetch head 0 while staging is in flight
    LOADH(qA, bA, vA, v3A, k3A, 3 * hf);
    __syncthreads();   // staging (and prefetch) complete

    #pragma unroll
    for (int p = 0; p < 3; ++p) {
        const int h = 3 * hf + p;
        if (p == 0) LOADH(qB, bB, vB, v3B, k3B, h + 1);
        if (p == 1) LOADH(qA, bA, vA, v3A, k3A, h + 1);

        const half4v* qf = (p == 1) ? qB : qA;
        const half4v* bf = (p == 1) ? bB : bA;
        const half4v* vf = (p == 1) ? vB : vA;
        const half4v* v3 = (p == 1) ? v3B : v3A;
        const half4v* k3 = (p == 1) ? k3B : k3A;

        // S^T = K * Q^T via 2x k=16 MFMAs per tj (frags straight from raw layouts)
        f32x4 st[4];
        #pragma unroll
        for (int tj = 0; tj < 4; ++tj) {
            half4v ka0, ka1;
            if (tj < 3) {
                ka0 = *(const half4v*)&sK[(size_t)h * 1536 + ((0 * 3 + tj) * 64 + lane) * 4];
                ka1 = *(const half4v*)&sK[(size_t)h * 1536 + ((1 * 3 + tj) * 64 + lane) * 4];
            } else {
                ka0 = k3[0];
                ka1 = k3[1];
            }
            f32x4 z = (f32x4){0.f, 0.f, 0.f, 0.f};
            z = __builtin_amdgcn_mfma_f32_16x16x16f16(ka0, qf[0], z, 0, 0, 0);
            st[tj] = __builtin_amdgcn_mfma_f32_16x16x16f16(ka1, qf[1], z, 0, 0, 0);
        }
        #pragma unroll
        for (int tj = 0; tj < 4; ++tj)
            #pragma unroll
            for (int r = 0; r < 4; ++r)
                st[tj][r] = st[tj][r] * SCALE + (float)bf[tj][r];

        // softmax (16 in-register + lane-pairs 16, 32 apart)
        float m = st[0][0];
        #pragma unroll
        for (int tj = 0; tj < 4; ++tj)
            #pragma unroll
            for (int r = 0; r < 4; ++r) m = fmaxf(m, st[tj][r]);
        m = fmaxf(m, __shfl_xor(m, 16));
        m = fmaxf(m, __shfl_xor(m, 32));
        float sum = 0.f;
        #pragma unroll
        for (int tj = 0; tj < 4; ++tj)
            #pragma unroll
            for (int r = 0; r < 4; ++r) {
                float e = __expf(st[tj][r] - m);
                st[tj][r] = e;
                sum += e;
            }
        sum += __shfl_xor(sum, 16);
        sum += __shfl_xor(sum, 32);
        float inv = 1.0f / sum;
        half4v pa[4];
        #pragma unroll
        for (int tj = 0; tj < 4; ++tj)
            pa[tj] = (half4v){(half_t)(st[tj][0] * inv), (half_t)(st[tj][1] * inv),
                              (half_t)(st[tj][2] * inv), (half_t)(st[tj][3] * inv)};

        // PV: O^T = V^T * P^T
        f32x4 o0 = (f32x4){0.f, 0.f, 0.f, 0.f};
        f32x4 o1 = (f32x4){0.f, 0.f, 0.f, 0.f};
        #pragma unroll
        for (int tj = 0; tj < 3; ++tj) {
            o0 = __builtin_amdgcn_mfma_f32_16x16x16f16(vf[2 * tj],     pa[tj], o0, 0, 0, 0);
            o1 = __builtin_amdgcn_mfma_f32_16x16x16f16(vf[2 * tj + 1], pa[tj], o1, 0, 0, 0);
        }
        o0 = __builtin_amdgcn_mfma_f32_16x16x16f16(v3[0], pa[3], o0, 0, 0, 0);
        o1 = __builtin_amdgcn_mfma_f32_16x16x16f16(v3[1], pa[3], o1, 0, 0, 0);

        // frag-major O store
        {
            int base = (((h * 4 + ti) * 64 + (g >> 1) * 16 + c) << 3) + (g & 1) * 4;
            *(half4v*)&sAf[base] =
                (half4v){(half_t)o0[0], (half_t)o0[1], (half_t)o0[2], (half_t)o0[3]};
            *(half4v*)&sAf[base + 256] =
                (half4v){(half_t)o1[0], (half_t)o1[1], (half_t)o1[2], (half_t)o1[3]};
        }
    }
#undef LOADH
    __syncthreads();

    // ---- out-projection + un-shift scatter -------------------------------
    {
        f32x4 pacc[6];
        float bo[6];
        #pragma unroll
        for (int q = 0; q < 6; ++q) {
            pacc[q] = (f32x4){0.f, 0.f, 0.f, 0.f};
            bo[q] = b_out[16 * (6 * hf + q) + c];
        }
        #pragma unroll
        for (int ks = 0; ks < 6; ++ks) {
            half8 aF = *(const half8*)&sAf[((ks * 4 + ti) * 64 + lane) * 8];
            #pragma unroll
            for (int q = 0; q < 6; ++q) {
                int ct = 6 * hf + q;
                half8 bF = *(const half8*)(wofrag + ((size_t)(ct * 6 + ks) * 64 + lane) * 8);
                pacc[q] = __builtin_amdgcn_mfma_f32_16x16x32_f16(aF, bF, pacc[q], 0, 0, 0);
            }
        }
        #pragma unroll
        for (int r = 0; r < 4; ++r) {
            int tok = 16 * ti + g * 4 + r;
            if (tok < 49) {
                int ty = tok / 7, tx = tok - ty * 7;
                int dy = nh * 7 + ty + 3; if (dy >= 56) dy -= 56;
                int dx = nw * 7 + tx + 3; if (dx >= 56) dx -= 56;
                float* op = out + ((size_t)b * 3136 + dy * 56 + dx) * 192;
                #pragma unroll
                for (int q = 0; q < 6; ++q)
                    op[16 * (6 * hf + q) + c] = pacc[q][r] + bo[q];
            }
        }
    }
}

// ---------------------------------------------------------------------------
extern "C" void kernel_launch(void* const* d_in, const int* in_sizes, int n_in,
                              void* d_out, int out_size, void* d_ws, size_t ws_size,
                              hipStream_t stream) {
    const float* x       = (const float*)d_in[0];
    const float* w_qkv   = (const float*)d_in[1];
    const float* b_qkv   = (const float*)d_in[2];
    const float* w_out   = (const float*)d_in[3];
    const float* b_out   = (const float*)d_in[4];
    const float* pos_enc = (const float*)d_in[5];
    float* out = (float*)d_out;

    half_t* wqf   = (half_t*)d_ws;                          // K1 weights (then mb16)
    half_t* mb16  = (half_t*)d_ws;                          // bias table (after K1)
    half_t* wof   = (half_t*)((char*)d_ws + 221184);
    half_t* qraw  = (half_t*)((char*)d_ws + 294912);
    half_t* kraw  = (half_t*)((char*)d_ws + 38043648);
    half_t* vraw  = (half_t*)((char*)d_ws + 75792384);
    half_t* tinyQ = (half_t*)((char*)d_ws + 113541120);
    half_t* tinyK = (half_t*)((char*)d_ws + 114327552);
    half_t* tinyV = (half_t*)((char*)d_ws + 115113984);

    convert_w<<<dim3(576), dim3(256), 0, stream>>>(w_qkv, w_out, wqf, wof);
    swin_qkv<<<dim3(2048), dim3(256), 0, stream>>>(
        x, wqf, b_qkv, qraw, kraw, vraw, tinyQ, tinyK, tinyV);
    build_bias<<<dim3(384), dim3(256), 0, stream>>>(pos_enc, mb16);
    swin_attn_proj<<<dim3(2048), dim3(512), 0, stream>>>(
        qraw, kraw, vraw, tinyQ, tinyK, tinyV, mb16, wof, b_out, out);
}

// Round 16
// 135.188 us; speedup vs baseline: 1.0782x; 1.0782x over previous
//
#include <hip/hip_runtime.h>
#include <hip/hip_bf16.h>
#include <cstddef>
#include <cstdint>

typedef _Float16 half_t;
typedef _Float16 half8  __attribute__((ext_vector_type(8)));
typedef _Float16 half4v __attribute__((ext_vector_type(4)));
typedef float    f32x4  __attribute__((ext_vector_type(4)));

#define SCALE 0.17677669529663687f   // 1/sqrt(32)

// workspace layout (bytes):
//   [0,      221184)  wqfrag fragment-major qkv weights fp16
//   [221184, 294912)  wofrag fragment-major out-proj weights fp16
//   [294912, 491520)  mb16[4][6][64][64] fp16 masked rel-pos bias table

// ---------------------------------------------------------------------------
__global__ __launch_bounds__(256) void convert_w(
    const float* __restrict__ w_qkv, const float* __restrict__ w_out,
    half_t* __restrict__ wq, half_t* __restrict__ wo)
{
    int i = blockIdx.x * 256 + threadIdx.x;
    if (i < 110592) {
        int u8 = i >> 3, e = i & 7;
        int c  = u8 & 15;
        int g  = (u8 >> 4) & 3;
        int ks = (u8 >> 6) % 6;
        int ct = u8 / 384;
        wq[i] = (half_t)w_qkv[(16 * ct + c) * 192 + ks * 32 + g * 8 + e];
    } else {
        int j = i - 110592;
        if (j < 36864) {
            int u8 = j >> 3, e = j & 7;
            int c  = u8 & 15;
            int g  = (u8 >> 4) & 3;
            int ks = (u8 >> 6) % 6;
            int q  = u8 / 384;
            wo[j] = (half_t)w_out[(16 * q + c) * 192 + ks * 32 + g * 8 + e];
        }
    }
}

// ---------------------------------------------------------------------------
__global__ __launch_bounds__(256) void build_bias(
    const float* __restrict__ pos_enc, half_t* __restrict__ mb)
{
    int idx = blockIdx.x * 256 + threadIdx.x;   // < 98304
    int j   = idx & 63;
    int i   = (idx >> 6) & 63;
    int hmc = idx >> 12;
    int h   = hmc % 6, mc = hmc / 6;
    float v = -60000.f;
    if (i < 49 && j < 49) {
        int yi = i / 7, xi = i - 7 * yi;
        int yj = j / 7, xj = j - 7 * yj;
        int ri = ((mc & 2) ? (yi < 4 ? 1 : 2) : 0) * 3 + ((mc & 1) ? (xi < 4 ? 1 : 2) : 0);
        int rj = ((mc & 2) ? (yj < 4 ? 1 : 2) : 0) * 3 + ((mc & 1) ? (xj < 4 ? 1 : 2) : 0);
        if (ri == rj) v = pos_enc[h * 169 + (yi - yj + 6) * 13 + (xi - xj + 6)];
    }
    mb[idx] = (half_t)v;
}

// ---------------------------------------------------------------------------
// Fully fused Swin attention. grid = 2048 (one window), 512 thr = 8 waves.
// Wave = (ti = wave&3, hf = wave>>2); heads h = 3*hf + p, rows 16ti..16ti+15.
// Phase 1: each wave computes its OWN q frags (registers) + its heads' k/V
//          frags for tile ti into LDS (frag-major, conflict-free). 1 barrier.
// Phase 2: r14's verified attention core, frags from regs/LDS. 1 barrier.
// Phase 3: r14's out-projection + un-shift scatter.
// LDS = 62208 B -> 2 blocks/CU.
// ---------------------------------------------------------------------------
__global__ __launch_bounds__(512, 4) void swin_fused(
    const float*  __restrict__ x,
    const half_t* __restrict__ wqfrag,
    const float*  __restrict__ b_qkv,
    const half_t* __restrict__ mb16,
    const half_t* __restrict__ wofrag,
    const float*  __restrict__ b_out,
    float* __restrict__ out)
{
    __shared__ __align__(16) half_t sKf[6 * 2 * 3 * 256];   // 18432 B k^T frags
    __shared__ __align__(16) half_t sVf[6 * 2 * 3 * 256];   // 18432 B V frags
    __shared__ __align__(16) half_t sKt[6 * 2 * 16];        // 384 B (token 48)
    __shared__ __align__(16) half_t sVt[6 * 2 * 16];        // 384 B
    __shared__ __align__(16) half_t sAf[6 * 4 * 64 * 8];    // 24576 B O frags

    const int w    = blockIdx.x;
    const int b    = w >> 6, win = w & 63, nh = win >> 3, nw = win & 7;
    const int tid  = threadIdx.x;
    const int wave = tid >> 6, lane = tid & 63;
    const int c    = lane & 15, g = lane >> 4;
    const int ti   = wave & 3, hf = wave >> 2;
    const int i_tok = 16 * ti + c;
    const int mc   = 2 * (nh == 7) + (nw == 7);

    // ---- phase 1: gather x rows of tile ti into fragments -----------------
    half8 xf[6];
    if (i_tok < 49) {
        int ty = i_tok / 7, tx = i_tok - ty * 7;
        int sy = nh * 7 + ty + 3; if (sy >= 56) sy -= 56;
        int sx = nw * 7 + tx + 3; if (sx >= 56) sx -= 56;
        const float* xr = x + ((size_t)b * 3136 + sy * 56 + sx) * 192 + g * 8;
        #pragma unroll
        for (int ks = 0; ks < 6; ++ks) {
            float4 v0 = *(const float4*)(xr + ks * 32);
            float4 v1 = *(const float4*)(xr + ks * 32 + 4);
            xf[ks] = (half8){(half_t)v0.x, (half_t)v0.y, (half_t)v0.z, (half_t)v0.w,
                             (half_t)v1.x, (half_t)v1.y, (half_t)v1.z, (half_t)v1.w};
        }
    } else {
        #pragma unroll
        for (int ks = 0; ks < 6; ++ks)
            xf[ks] = (half8){(half_t)0.f, (half_t)0.f, (half_t)0.f, (half_t)0.f,
                             (half_t)0.f, (half_t)0.f, (half_t)0.f, (half_t)0.f};
    }

    // ---- q (kind 0): swapped operands, results stay in registers ----------
    half4v qf[3][2];
    #pragma unroll
    for (int p = 0; p < 3; ++p) {
        #pragma unroll
        for (int dh = 0; dh < 2; ++dh) {
            const int h  = 3 * hf + p;
            const int ct = h * 2 + dh;
            const half_t* wp = wqfrag + ((size_t)ct * 384 + lane) * 8;
            half8 bfm[6];
            #pragma unroll
            for (int ks = 0; ks < 6; ++ks) bfm[ks] = *(const half8*)(wp + ks * 512);
            f32x4 a0 = (f32x4){0.f, 0.f, 0.f, 0.f};
            #pragma unroll
            for (int ks = 0; ks < 6; ++ks)
                a0 = __builtin_amdgcn_mfma_f32_16x16x32_f16(bfm[ks], xf[ks], a0, 0, 0, 0);
            float4 bq = *(const float4*)(b_qkv + 16 * ct + 4 * g);
            half4v pv = (half4v){(half_t)(a0[0] + bq.x), (half_t)(a0[1] + bq.y),
                                 (half_t)(a0[2] + bq.z), (half_t)(a0[3] + bq.w)};
            if (ti < 3) {
                qf[p][dh] = pv;
            } else {
                // replicate lane (c==0, g) across its 16-lane group
                union { half4v h; int i2[2]; } u; u.h = pv;
                u.i2[0] = __shfl(u.i2[0], lane & 48);
                u.i2[1] = __shfl(u.i2[1], lane & 48);
                qf[p][dh] = u.h;
            }
        }
    }

    // ---- k (kind 1): swapped operands -> LDS frag-major -------------------
    #pragma unroll
    for (int p = 0; p < 3; ++p) {
        #pragma unroll
        for (int dh = 0; dh < 2; ++dh) {
            const int h  = 3 * hf + p;
            const int ct = 12 + h * 2 + dh;
            const half_t* wp = wqfrag + ((size_t)ct * 384 + lane) * 8;
            half8 bfm[6];
            #pragma unroll
            for (int ks = 0; ks < 6; ++ks) bfm[ks] = *(const half8*)(wp + ks * 512);
            f32x4 a0 = (f32x4){0.f, 0.f, 0.f, 0.f};
            #pragma unroll
            for (int ks = 0; ks < 6; ++ks)
                a0 = __builtin_amdgcn_mfma_f32_16x16x32_f16(bfm[ks], xf[ks], a0, 0, 0, 0);
            float4 bq = *(const float4*)(b_qkv + 16 * ct + 4 * g);
            half4v pv = (half4v){(half_t)(a0[0] + bq.x), (half_t)(a0[1] + bq.y),
                                 (half_t)(a0[2] + bq.z), (half_t)(a0[3] + bq.w)};
            if (ti < 3) {
                *(half4v*)&sKf[h * 1536 + dh * 768 + ti * 256 + lane * 4] = pv;
            } else if (c == 0) {
                *(half4v*)&sKt[(h * 2 + dh) * 16 + 4 * g] = pv;
            }
        }
    }

    // ---- V (kind 2): normal operands -> LDS frag-major --------------------
    #pragma unroll
    for (int p = 0; p < 3; ++p) {
        #pragma unroll
        for (int dh = 0; dh < 2; ++dh) {
            const int h  = 3 * hf + p;
            const int ct = 24 + h * 2 + dh;
            const half_t* wp = wqfrag + ((size_t)ct * 384 + lane) * 8;
            half8 bfm[6];
            #pragma unroll
            for (int ks = 0; ks < 6; ++ks) bfm[ks] = *(const half8*)(wp + ks * 512);
            f32x4 a0 = (f32x4){0.f, 0.f, 0.f, 0.f};
            #pragma unroll
            for (int ks = 0; ks < 6; ++ks)
                a0 = __builtin_amdgcn_mfma_f32_16x16x32_f16(xf[ks], bfm[ks], a0, 0, 0, 0);
            const float bv = b_qkv[16 * ct + c];
            if (ti < 3) {
                half4v pv = (half4v){(half_t)(a0[0] + bv), (half_t)(a0[1] + bv),
                                     (half_t)(a0[2] + bv), (half_t)(a0[3] + bv)};
                *(half4v*)&sVf[h * 1536 + dh * 768 + ti * 256 + lane * 4] = pv;
            } else if (g == 0) {
                sVt[(h * 2 + dh) * 16 + c] = (half_t)(a0[0] + bv);
            }
        }
    }
    __syncthreads();

    // ---- phase 2: attention (r14-verified core) ---------------------------
    half4v bA[4], bB[4];
    {
        const half_t* mrow = mb16 + ((size_t)(mc * 6 + 3 * hf) * 64 + i_tok) * 64;
        #pragma unroll
        for (int tj = 0; tj < 4; ++tj)
            bA[tj] = *(const half4v*)(mrow + 16 * tj + 4 * g);
    }

    #pragma unroll
    for (int p = 0; p < 3; ++p) {
        const int h = 3 * hf + p;
        if (p == 0) {
            const half_t* mrow = mb16 + ((size_t)(mc * 6 + h + 1) * 64 + i_tok) * 64;
            #pragma unroll
            for (int tj = 0; tj < 4; ++tj) bB[tj] = *(const half4v*)(mrow + 16 * tj + 4 * g);
        }
        if (p == 1) {
            const half_t* mrow = mb16 + ((size_t)(mc * 6 + h + 1) * 64 + i_tok) * 64;
            #pragma unroll
            for (int tj = 0; tj < 4; ++tj) bA[tj] = *(const half4v*)(mrow + 16 * tj + 4 * g);
        }
        const half4v* bf = (p == 1) ? bB : bA;

        // S^T = K * Q^T via 2x k=16 MFMAs per tj
        f32x4 st[4];
        #pragma unroll
        for (int tj = 0; tj < 4; ++tj) {
            half4v ka0, ka1;
            if (tj < 3) {
                ka0 = *(const half4v*)&sKf[h * 1536 + 0 * 768 + tj * 256 + lane * 4];
                ka1 = *(const half4v*)&sKf[h * 1536 + 1 * 768 + tj * 256 + lane * 4];
            } else {
                ka0 = *(const half4v*)&sKt[(h * 2 + 0) * 16 + 4 * g];
                ka1 = *(const half4v*)&sKt[(h * 2 + 1) * 16 + 4 * g];
            }
            f32x4 z = (f32x4){0.f, 0.f, 0.f, 0.f};
            z = __builtin_amdgcn_mfma_f32_16x16x16f16(ka0, qf[p][0], z, 0, 0, 0);
            st[tj] = __builtin_amdgcn_mfma_f32_16x16x16f16(ka1, qf[p][1], z, 0, 0, 0);
        }
        #pragma unroll
        for (int tj = 0; tj < 4; ++tj)
            #pragma unroll
            for (int r = 0; r < 4; ++r)
                st[tj][r] = st[tj][r] * SCALE + (float)bf[tj][r];

        // softmax (16 in-register + lane-pairs 16, 32 apart)
        float m = st[0][0];
        #pragma unroll
        for (int tj = 0; tj < 4; ++tj)
            #pragma unroll
            for (int r = 0; r < 4; ++r) m = fmaxf(m, st[tj][r]);
        m = fmaxf(m, __shfl_xor(m, 16));
        m = fmaxf(m, __shfl_xor(m, 32));
        float sum = 0.f;
        #pragma unroll
        for (int tj = 0; tj < 4; ++tj)
            #pragma unroll
            for (int r = 0; r < 4; ++r) {
                float e = __expf(st[tj][r] - m);
                st[tj][r] = e;
                sum += e;
            }
        sum += __shfl_xor(sum, 16);
        sum += __shfl_xor(sum, 32);
        float inv = 1.0f / sum;
        half4v pa[4];
        #pragma unroll
        for (int tj = 0; tj < 4; ++tj)
            pa[tj] = (half4v){(half_t)(st[tj][0] * inv), (half_t)(st[tj][1] * inv),
                              (half_t)(st[tj][2] * inv), (half_t)(st[tj][3] * inv)};

        // PV: O^T = V^T * P^T
        f32x4 o0 = (f32x4){0.f, 0.f, 0.f, 0.f};
        f32x4 o1 = (f32x4){0.f, 0.f, 0.f, 0.f};
        #pragma unroll
        for (int tj = 0; tj < 3; ++tj) {
            half4v v0 = *(const half4v*)&sVf[h * 1536 + 0 * 768 + tj * 256 + lane * 4];
            half4v v1 = *(const half4v*)&sVf[h * 1536 + 1 * 768 + tj * 256 + lane * 4];
            o0 = __builtin_amdgcn_mfma_f32_16x16x16f16(v0, pa[tj], o0, 0, 0, 0);
            o1 = __builtin_amdgcn_mfma_f32_16x16x16f16(v1, pa[tj], o1, 0, 0, 0);
        }
        {
            half_t tv0 = sVt[(h * 2 + 0) * 16 + c];
            half_t tv1 = sVt[(h * 2 + 1) * 16 + c];
            half4v v30 = (half4v){tv0, tv0, tv0, tv0};
            half4v v31 = (half4v){tv1, tv1, tv1, tv1};
            o0 = __builtin_amdgcn_mfma_f32_16x16x16f16(v30, pa[3], o0, 0, 0, 0);
            o1 = __builtin_amdgcn_mfma_f32_16x16x16f16(v31, pa[3], o1, 0, 0, 0);
        }
        // frag-major O store
        {
            int base = (((h * 4 + ti) * 64 + (g >> 1) * 16 + c) << 3) + (g & 1) * 4;
            *(half4v*)&sAf[base] =
                (half4v){(half_t)o0[0], (half_t)o0[1], (half_t)o0[2], (half_t)o0[3]};
            *(half4v*)&sAf[base + 256] =
                (half4v){(half_t)o1[0], (half_t)o1[1], (half_t)o1[2], (half_t)o1[3]};
        }
    }
    __syncthreads();

    // ---- phase 3: out-projection + un-shift scatter -----------------------
    {
        f32x4 pacc[6];
        float bo[6];
        #pragma unroll
        for (int q = 0; q < 6; ++q) {
            pacc[q] = (f32x4){0.f, 0.f, 0.f, 0.f};
            bo[q] = b_out[16 * (6 * hf + q) + c];
        }
        #pragma unroll
        for (int ks = 0; ks < 6; ++ks) {
            half8 aF = *(const half8*)&sAf[((ks * 4 + ti) * 64 + lane) * 8];
            #pragma unroll
            for (int q = 0; q < 6; ++q) {
                int ct = 6 * hf + q;
                half8 bF = *(const half8*)(wofrag + ((size_t)(ct * 6 + ks) * 64 + lane) * 8);
                pacc[q] = __builtin_amdgcn_mfma_f32_16x16x32_f16(aF, bF, pacc[q], 0, 0, 0);
            }
        }
        #pragma unroll
        for (int r = 0; r < 4; ++r) {
            int tok = 16 * ti + g * 4 + r;
            if (tok < 49) {
                int ty = tok / 7, tx = tok - ty * 7;
                int dy = nh * 7 + ty + 3; if (dy >= 56) dy -= 56;
                int dx = nw * 7 + tx + 3; if (dx >= 56) dx -= 56;
                float* op = out + ((size_t)b * 3136 + dy * 56 + dx) * 192;
                #pragma unroll
                for (int q = 0; q < 6; ++q)
                    op[16 * (6 * hf + q) + c] = pacc[q][r] + bo[q];
            }
        }
    }
}

// ---------------------------------------------------------------------------
extern "C" void kernel_launch(void* const* d_in, const int* in_sizes, int n_in,
                              void* d_out, int out_size, void* d_ws, size_t ws_size,
                              hipStream_t stream) {
    const float* x       = (const float*)d_in[0];
    const float* w_qkv   = (const float*)d_in[1];
    const float* b_qkv   = (const float*)d_in[2];
    const float* w_out   = (const float*)d_in[3];
    const float* b_out   = (const float*)d_in[4];
    const float* pos_enc = (const float*)d_in[5];
    float* out = (float*)d_out;

    half_t* wqf  = (half_t*)d_ws;
    half_t* wof  = (half_t*)((char*)d_ws + 221184);
    half_t* mb16 = (half_t*)((char*)d_ws + 294912);

    convert_w<<<dim3(576), dim3(256), 0, stream>>>(w_qkv, w_out, wqf, wof);
    build_bias<<<dim3(384), dim3(256), 0, stream>>>(pos_enc, mb16);
    swin_fused<<<dim3(2048), dim3(512), 0, stream>>>(
        x, wqf, b_qkv, mb16, wof, b_out, out);
}